// Round 8
// baseline (855.900 us; speedup 1.0000x reference)
//
#include <hip/hip_runtime.h>
#include <hip/hip_bf16.h>
#include <stdint.h>

// Problem constants
#define E_TOTAL 800000
#define NNODES  50000
#define NGRAPHS 64
#define NPRED   8
#define MPAD    50048          // node rows padded to 128 (391*128)
#define EBLK    6250           // 800000/128 edge blocks
#define NBLK    391            // MPAD/128 node blocks

// Weight tile: 320 rows (out-cols) x 64 k x bf16 = 40 KB, stored pre-swizzled
// (16B chunk index XOR (row&7)) so linear global_load_lds yields the swizzled
// LDS image directly.
#define TILE_B  40960
#define SCR_B   81920          // block scratch: 128 rows x 320 cols bf16 (640B rows)
#define LDSZ    (2*TILE_B + SCR_B)   // 163840 = 160 KiB exactly

typedef short v8s __attribute__((ext_vector_type(8)));
typedef float v4f __attribute__((ext_vector_type(4)));
typedef float f4  __attribute__((ext_vector_type(4)));

__device__ __forceinline__ void gload_lds16(const void* g, void* l) {
    __builtin_amdgcn_global_load_lds(
        (const __attribute__((address_space(1))) uint32_t*)g,
        (__attribute__((address_space(3))) uint32_t*)l, 16, 0, 0);
}

__device__ __forceinline__ short f2bf_s(float f) {
    __hip_bfloat16 h = __float2bfloat16(f);
    return *reinterpret_cast<short*>(&h);
}

// ---------------------------------------------------------------------------
// Fused MLP chain. EDGE: gather(x,ei,ea) -> L1 -> L2 -> L3 -> msg(128)
//                        -> atomic scatter into aggr.
//        !EDGE: aggrb(128) -> L1 -> L2 -> L3 -> L4(320) -> node fp32 store.
// 512 threads = 8 waves, 2x4 grid: wave (wr,wc) owns 64 rows x 80 cols
// (4 row-panels of 16). Per K=64 tile/wave: 10 B-frag + 8 A-frag ds_read_b128
// for 40 MFMAs. acc = 4x5 v4f (80 VGPR). Weight K=64 tiles stream through a
// 2-slot LDS ping-pong, ONE barrier per tile:
//   [vmcnt(0); barrier; stage(t+1 -> slot^1); compute(t)]
// vmcnt(0)-before-barrier publishes each wave's tile-t loads; the barrier also
// proves all waves finished tile t-1, so staging into its slot is safe.
// Layer turnaround via block-shared swizzled LDS scratch; DUMP is guarded by
// its own leading barrier (readers of old scratch done) and trailing
// lgkmcnt(0) (writes drained before the next tile's publishing barrier).
// ---------------------------------------------------------------------------
template <bool EDGE>
__global__ __launch_bounds__(512)
void chain_kernel(const float* __restrict__ x, const int* __restrict__ ei,
                  const float* __restrict__ ea,
                  const __hip_bfloat16* __restrict__ aggrb,
                  const char* __restrict__ wimg,
                  const float* __restrict__ b1, const float* __restrict__ b2,
                  const float* __restrict__ b3, const float* __restrict__ b4,
                  float* __restrict__ outp)
{
    __shared__ __align__(16) char lds[LDSZ];
    const int tid  = threadIdx.x;
    const int lane = tid & 63;
    const int wave = tid >> 6;
    const int wr   = wave >> 2;   // 0..1 (64-row half)
    const int wc   = wave & 3;    // 0..3 (80-col quarter)
    const int l15  = lane & 15;
    const int kk   = lane >> 4;   // 0..3
    char* scr = lds + 2*TILE_B;
    const int rowbase = blockIdx.x*128 + wr*64;

    constexpr int KT1 = EDGE ? 1 : 2;   // L1 K-tiles (K=64 / K=128)
    constexpr int T   = KT1 + 15;       // + 5+5+5

    auto stagef = [&](int t, int slot_){
        const char* s = wimg + (size_t)t*TILE_B + (size_t)tid*16;
        char* d = lds + slot_*TILE_B + wave*1024;   // wave-uniform dest (+lane*16 hw)
#pragma unroll
        for (int i = 0; i < 5; ++i) gload_lds16(s + i*8192, d + i*8192);
    };

    v4f acc[4][5];
#pragma unroll
    for (int p = 0; p < 4; ++p)
#pragma unroll
        for (int n = 0; n < 5; ++n) acc[p][n] = (v4f){0.f,0.f,0.f,0.f};

    // ---- bias preload into registers ----
    float bb1[5], bb2[5], bb3[5], bb4[5];
#pragma unroll
    for (int n = 0; n < 5; ++n) {
        int colb = wc*80 + n*16 + l15;
        bb1[n] = b1[colb]; bb2[n] = b2[colb]; bb3[n] = b3[colb];
        if (EDGE) bb4[n] = (n < 2) ? b4[wc*32 + n*16 + l15] : 0.f;
        else      bb4[n] = b4[colb];
    }

    // ---- L1 A-fragments (4 panels x KT1 tiles x 2 halves) ----
    v8s af1[KT1][4][2];
    if (EDGE) {
#pragma unroll
        for (int p = 0; p < 4; ++p) {
            const int e = rowbase + p*16 + l15;
            // k-half 0: kk 0,1 -> x[dst][0..7 / 8..15]; kk 2,3 -> x[src][...]
            const int nidx = (kk < 2) ? ei[E_TOTAL + e] : ei[e];
            const float* xs = x + (size_t)nidx*16 + (kk & 1)*8;
            f4 p0 = *(const f4*)xs, p1 = *(const f4*)(xs + 4);
            v8s a0, a1;
#pragma unroll
            for (int j = 0; j < 4; ++j) { a0[j] = f2bf_s(p0[j]); a0[4+j] = f2bf_s(p1[j]); }
            if (kk == 0) {        // k-half 1: k 32..39 = edge_attr, rest zero
                const float* es = ea + (size_t)e*8;
                f4 q0 = *(const f4*)es, q1 = *(const f4*)(es + 4);
#pragma unroll
                for (int j = 0; j < 4; ++j) { a1[j] = f2bf_s(q0[j]); a1[4+j] = f2bf_s(q1[j]); }
            } else {
#pragma unroll
                for (int j = 0; j < 8; ++j) a1[j] = 0;
            }
            af1[0][p][0] = a0; af1[0][p][1] = a1;
        }
    } else {
#pragma unroll
        for (int p = 0; p < 4; ++p) {
            const int grow = rowbase + p*16 + l15;
#pragma unroll
            for (int t2 = 0; t2 < KT1; ++t2)
#pragma unroll
                for (int h = 0; h < 2; ++h)
                    af1[t2][p][h] = *(const v8s*)((const char*)aggrb +
                        (size_t)grow*256 + t2*128 + h*64 + kk*16);
        }
    }

    stagef(0, 0);
    int tt = 0, slot = 0;

#define TILE_BEGIN()                                                            \
    { asm volatile("s_waitcnt vmcnt(0)" ::: "memory");                          \
      __builtin_amdgcn_s_barrier();                                             \
      if (tt + 1 < T) stagef(tt + 1, slot ^ 1); }

#define TILE_END()  { ++tt; slot ^= 1; }

// B-frag: row r_ = out-col, 128B rows (8 chunks of 16B), chunk (h*4+kk)^(r_&7)
#define MFMA_TILE(A_, NT_, CB_)                                                 \
    { const char* sl_ = lds + slot*TILE_B;                                      \
      _Pragma("unroll")                                                         \
      for (int h_ = 0; h_ < 2; ++h_) {                                          \
        _Pragma("unroll")                                                       \
        for (int n_ = 0; n_ < NT_; ++n_) {                                      \
          int r_ = (CB_) + n_*16 + l15;                                         \
          v8s b_ = *(const v8s*)(sl_ + r_*128 + ((((h_<<2)|kk) ^ (r_&7))<<4));  \
          _Pragma("unroll")                                                     \
          for (int p_ = 0; p_ < 4; ++p_)                                        \
            acc[p_][n_] = __builtin_amdgcn_mfma_f32_16x16x32_bf16(              \
                (A_)[p_][h_], b_, acc[p_][n_], 0, 0, 0);                        \
        } } }

// A-frag from scratch: row = wr*64+p*16+l15 (640B rows), chunk (kt*8+h*4+kk)^(l15&7)
#define LOAD_AFRAG(KT_, A_)                                                     \
    { _Pragma("unroll")                                                         \
      for (int p_ = 0; p_ < 4; ++p_)                                            \
        _Pragma("unroll")                                                       \
        for (int h_ = 0; h_ < 2; ++h_) {                                        \
          int c_ = ((KT_)*8 + h_*4 + kk) ^ (l15 & 7);                           \
          (A_)[p_][h_] = *(const v8s*)(scr + (wr*64 + p_*16 + l15)*640 + (c_<<4)); \
        } }

// Dump acc (C layout: col=n*16+l15+wc*80, row=wr*64+p*16+kk*4+rr) -> scratch,
// bf16, 640B rows, 16B chunk XOR (row&7); reset acc; drain writes.
#define DUMP_RELU(BB_)                                                          \
    { __builtin_amdgcn_s_barrier();  /* readers of old scratch are done */      \
      _Pragma("unroll")                                                         \
      for (int p_ = 0; p_ < 4; ++p_)                                            \
        _Pragma("unroll")                                                       \
        for (int n_ = 0; n_ < 5; ++n_) {                                        \
          int col_ = wc*80 + n_*16 + l15;                                       \
          _Pragma("unroll")                                                     \
          for (int rr_ = 0; rr_ < 4; ++rr_) {                                   \
            int row_ = wr*64 + p_*16 + kk*4 + rr_;                              \
            float v_ = fmaxf(acc[p_][n_][rr_] + (BB_)[n_], 0.f);                \
            *(__hip_bfloat16*)(scr + row_*640 +                                 \
                (((col_>>3) ^ (row_&7))<<4) + (col_&7)*2) = __float2bfloat16(v_); \
          }                                                                     \
          acc[p_][n_] = (v4f){0.f,0.f,0.f,0.f};                                 \
        }                                                                       \
      asm volatile("s_waitcnt lgkmcnt(0)" ::: "memory"); }

    // ---- L1 ----
#pragma unroll
    for (int kt = 0; kt < KT1; ++kt) { TILE_BEGIN(); MFMA_TILE(af1[kt], 5, wc*80); TILE_END(); }
    DUMP_RELU(bb1);
    // ---- L2 ----
#pragma unroll
    for (int kt = 0; kt < 5; ++kt) {
        TILE_BEGIN(); v8s A_[4][2]; LOAD_AFRAG(kt, A_); MFMA_TILE(A_, 5, wc*80); TILE_END();
    }
    DUMP_RELU(bb2);
    // ---- L3 ----
#pragma unroll
    for (int kt = 0; kt < 5; ++kt) {
        TILE_BEGIN(); v8s A_[4][2]; LOAD_AFRAG(kt, A_); MFMA_TILE(A_, 5, wc*80); TILE_END();
    }
    DUMP_RELU(bb3);
    // ---- L4 ----
    if (EDGE) {
#pragma unroll
        for (int kt = 0; kt < 5; ++kt) {
            TILE_BEGIN(); v8s A_[4][2]; LOAD_AFRAG(kt, A_); MFMA_TILE(A_, 2, wc*32); TILE_END();
        }
        // fused scatter-add: aggr[dst[e]*128 + col] += msg
#pragma unroll
        for (int p = 0; p < 4; ++p) {
#pragma unroll
            for (int rr = 0; rr < 4; ++rr) {
                int erow = rowbase + p*16 + kk*4 + rr;
                int d = ei[E_TOTAL + erow];
                float* ag = outp + (size_t)d*128;
#pragma unroll
                for (int n = 0; n < 2; ++n) {
                    int col = wc*32 + n*16 + l15;
                    atomicAdd(ag + col, acc[p][n][rr] + bb4[n]);
                }
            }
        }
    } else {
#pragma unroll
        for (int kt = 0; kt < 5; ++kt) {
            TILE_BEGIN(); v8s A_[4][2]; LOAD_AFRAG(kt, A_); MFMA_TILE(A_, 5, wc*80); TILE_END();
        }
        // store node fp32 [MPAD][320]
#pragma unroll
        for (int p = 0; p < 4; ++p) {
#pragma unroll
            for (int n = 0; n < 5; ++n) {
                int col = wc*80 + n*16 + l15;
#pragma unroll
                for (int rr = 0; rr < 4; ++rr) {
                    int grow = rowbase + p*16 + kk*4 + rr;
                    outp[(size_t)grow*320 + col] = acc[p][n][rr] + bb4[n];
                }
            }
        }
    }
#undef TILE_BEGIN
#undef TILE_END
#undef MFMA_TILE
#undef LOAD_AFRAG
#undef DUMP_RELU
}

// ---------------------------------------------------------------------------
// Repack fp32 W [K][N] -> pre-swizzled bf16 K=64 tile stream (KT tiles,
// each 320 rows x 64 k, chunk index XOR (row&7)).
// ---------------------------------------------------------------------------
__global__ void repack_tiles(const float* __restrict__ src, char* __restrict__ img,
                             int K, int N, int KT)
{
    int t = blockIdx.x*256 + threadIdx.x;
    if (t >= KT*20480) return;
    int k64  = t & 63;
    int r    = (t >> 6) % 320;     // row = out col
    int tile = t / 20480;
    int kg   = tile*64 + k64;
    float v = (r < N && kg < K) ? src[(size_t)kg*N + r] : 0.f;
    size_t addr = (size_t)tile*TILE_B + (size_t)r*128 +
                  ((((k64>>3) ^ (r&7)))<<4) + (k64&7)*2;
    *(__hip_bfloat16*)(img + addr) = __float2bfloat16(v);
}

__global__ void pad_bias(const float* __restrict__ src, float* __restrict__ dst,
                         int N, int Npad)
{
    int t = blockIdx.x*256 + threadIdx.x;
    if (t < Npad) dst[t] = (t < N) ? src[t] : 0.f;
}

// aggr fp32 [MPAD][128] -> bf16 (rows >= NNODES forced to 0)
__global__ void cvt_aggr(const float* __restrict__ aggr, __hip_bfloat16* __restrict__ out)
{
    int t = blockIdx.x*256 + threadIdx.x;
    int row = t >> 7;
    float v = (row < NNODES) ? aggr[t] : 0.f;
    out[t] = __float2bfloat16(v);
}

__global__ void graph_starts_kernel(const int* __restrict__ batch,
                                    int* __restrict__ starts)
{
    int g = threadIdx.x;
    if (g > NGRAPHS) return;
    int lo = 0, hi = NNODES;
    while (lo < hi) {
        int mid = (lo + hi) >> 1;
        if (batch[mid] < g) lo = mid + 1; else hi = mid;
    }
    starts[g] = lo;
}

// Mean pool: node fp32 [MPAD][320] (valid cols 0..299) -> pooled [64][300]
__global__ void pool_kernel(const float* __restrict__ node,
                            const int* __restrict__ starts,
                            float* __restrict__ pooled)
{
    __shared__ float red[8][32];
    int g   = blockIdx.x;
    int col = blockIdx.y*32 + (threadIdx.x & 31);
    int rl  = threadIdx.x >> 5;
    int s = starts[g], e = starts[g + 1];
    float sum = 0.f;
    if (col < 300)
        for (int i = s + rl; i < e; i += 8) sum += node[(size_t)i*320 + col];
    red[rl][threadIdx.x & 31] = sum;
    __syncthreads();
    if (rl == 0 && col < 300) {
        float tot = 0.f;
#pragma unroll
        for (int r = 0; r < 8; ++r) tot += red[r][threadIdx.x & 31];
        float cnt = (float)(e - s);
        pooled[g*300 + col] = tot / fmaxf(cnt, 1.0f);
    }
}

__global__ void final_kernel(const float* __restrict__ pooled,
                             const float* __restrict__ lw,
                             const float* __restrict__ lb,
                             float* __restrict__ out)
{
    int t = threadIdx.x;          // 512 = 64 * 8
    int g = t / NPRED, p = t % NPRED;
    float s = lb[p];
    for (int k = 0; k < 300; ++k)
        s = fmaf(pooled[g*300 + k], lw[k*NPRED + p], s);
    out[g*NPRED + p] = s;
}

// ---------------------------------------------------------------------------
extern "C" void kernel_launch(void* const* d_in, const int* in_sizes, int n_in,
                              void* d_out, int out_size, void* d_ws, size_t ws_size,
                              hipStream_t stream)
{
    const float* x     = (const float*)d_in[0];
    const int*   ei    = (const int*)d_in[1];
    const float* ea    = (const float*)d_in[2];
    const int*   batch = (const int*)d_in[3];
    const float* mw[4] = {(const float*)d_in[4], (const float*)d_in[6],
                          (const float*)d_in[8], (const float*)d_in[10]};
    const float* mb[4] = {(const float*)d_in[5], (const float*)d_in[7],
                          (const float*)d_in[9], (const float*)d_in[11]};
    const float* nw[4] = {(const float*)d_in[12], (const float*)d_in[14],
                          (const float*)d_in[16], (const float*)d_in[18]};
    const float* nb[4] = {(const float*)d_in[13], (const float*)d_in[15],
                          (const float*)d_in[17], (const float*)d_in[19]};
    const float* lw = (const float*)d_in[20];
    const float* lb = (const float*)d_in[21];
    float* out = (float*)d_out;

    char* ws = (char*)d_ws;
    size_t off = 0;
    auto alloc = [&](size_t bytes) -> void* {
        void* p = ws + off;
        off += (bytes + 255) & ~(size_t)255;
        return p;
    };

    float*          aggr   = (float*)alloc((size_t)MPAD*128*4);          // 25.6 MB
    __hip_bfloat16* aggrb  = (__hip_bfloat16*)alloc((size_t)MPAD*128*2); // 12.8 MB
    float*          node   = (float*)alloc((size_t)MPAD*320*4);          // 64.1 MB
    char*           wimg_e = (char*)alloc((size_t)16*TILE_B);            // 640 KB
    char*           wimg_n = (char*)alloc((size_t)17*TILE_B);            // 680 KB
    float* mbp[4]; float* nbp[4];
    for (int i = 0; i < 4; ++i) { mbp[i] = (float*)alloc(320*4); nbp[i] = (float*)alloc(320*4); }
    float* pooled = (float*)alloc(64*300*4);
    int*   starts = (int*)alloc(65*4);

    // ---- weight repack into pre-swizzled K=64 tile streams ----
    const int mK[4]  = {40, 300, 300, 300},  mN[4]  = {300, 300, 300, 128};
    const int nK[4]  = {128, 300, 300, 300}, nN[4]  = {300, 300, 300, 300};
    const int mKT[4] = {1, 5, 5, 5},         nKT[4] = {2, 5, 5, 5};
    {
        size_t te = 0, tn = 0;
        for (int i = 0; i < 4; ++i) {
            repack_tiles<<<mKT[i]*80, 256, 0, stream>>>(mw[i], wimg_e + te*TILE_B,
                                                        mK[i], mN[i], mKT[i]);
            te += mKT[i];
            repack_tiles<<<nKT[i]*80, 256, 0, stream>>>(nw[i], wimg_n + tn*TILE_B,
                                                        nK[i], nN[i], nKT[i]);
            tn += nKT[i];
            pad_bias<<<2, 256, 0, stream>>>(mb[i], mbp[i], mN[i], 320);
            pad_bias<<<2, 256, 0, stream>>>(nb[i], nbp[i], nN[i], 320);
        }
    }
    hipMemsetAsync(aggr, 0, (size_t)NNODES*128*4, stream);
    graph_starts_kernel<<<1, 128, 0, stream>>>(batch, starts);

    // ---- edge phase: ONE kernel for all 800K edges ----
    chain_kernel<true><<<EBLK, 512, 0, stream>>>(
        x, ei, ea, nullptr, wimg_e, mbp[0], mbp[1], mbp[2], mbp[3], aggr);

    // ---- node phase ----
    cvt_aggr<<<(MPAD*128)/256, 256, 0, stream>>>(aggr, aggrb);
    chain_kernel<false><<<NBLK, 512, 0, stream>>>(
        x, ei, ea, aggrb, wimg_n, nbp[0], nbp[1], nbp[2], nbp[3], node);

    pool_kernel<<<dim3(64, 10), 256, 0, stream>>>(node, starts, pooled);
    final_kernel<<<1, 512, 0, stream>>>(pooled, lw, lb, out);
}